// Round 9
// baseline (2647.658 us; speedup 1.0000x reference)
//
#include <hip/hip_runtime.h>

#define Bn  16
#define Ln  256
#define D0n 64
#define Hn  128
#define H4n 512
#define Kn  512
#define BLn 4096   // Bn*Ln

typedef float f4 __attribute__((ext_vector_type(4)));

__device__ __forceinline__ float sigf(float x) { return 1.0f / (1.0f + expf(-x)); }

__device__ __forceinline__ float fma4v(f4 w, f4 x, float acc) {
    acc = fmaf(w.x, x.x, acc);
    acc = fmaf(w.y, x.y, acc);
    acc = fmaf(w.z, x.z, acc);
    acc = fmaf(w.w, x.w, acc);
    return acc;
}

__device__ __forceinline__ float dotn(const f4* __restrict__ a,
                                      const f4* __restrict__ w, int n4) {
    float a0 = 0.f, a1 = 0.f, a2 = 0.f, a3 = 0.f;
    for (int i = 0; i < n4; i += 4) {
        a0 = fma4v(a[i], w[i], a0);
        a1 = fma4v(a[i + 1], w[i + 1], a1);
        a2 = fma4v(a[i + 2], w[i + 2], a2);
        a3 = fma4v(a[i + 3], w[i + 3], a3);
    }
    return (a0 + a1) + (a2 + a3);
}

// ---- tiled GEMM: Y[r][c] = scale*(X[r].W[c]) + b[c]; tiles 64r x 64c -------
__global__ __launch_bounds__(256)
void k_gemm(const float* __restrict__ X, const float* __restrict__ W,
            const float* __restrict__ b, float* __restrict__ Y,
            int K, int out_dim, int do_relu, float scale) {
    __shared__ f4 wt[4160];               // 64 x (K/4+1) max = 64x65
    const int K4 = K >> 2;
    const int st = K4 + 1;
    const int lg = __ffs(K4) - 1;
    const int tid = threadIdx.x;
    const int c = tid & 63, rpart = tid >> 6;
    const f4* W4 = (const f4*)W;
    const int per = (64 * K4) >> 8;       // K/16
    for (int i = 0; i < per; ++i) {
        int idx = i * 256 + tid;
        int row = idx >> lg, col = idx & (K4 - 1);
        wt[row * st + col] = W4[(size_t)(blockIdx.x * 64 + row) * K4 + col];
    }
    __syncthreads();
    const f4* X4 = (const f4*)X;
    const float bc = b ? b[blockIdx.x * 64 + c] : 0.f;
    const f4* wrow = wt + c * st;
    for (int i = 0; i < 16; ++i) {
        int r = blockIdx.y * 64 + i * 4 + rpart;
        const f4* xr = X4 + (size_t)r * K4;
        float a0 = 0.f, a1 = 0.f, a2 = 0.f, a3 = 0.f;
        for (int k = 0; k < K4; k += 4) {
            a0 = fma4v(wrow[k],     xr[k],     a0);
            a1 = fma4v(wrow[k + 1], xr[k + 1], a1);
            a2 = fma4v(wrow[k + 2], xr[k + 2], a2);
            a3 = fma4v(wrow[k + 3], xr[k + 3], a3);
        }
        float acc = scale * ((a0 + a1) + (a2 + a3)) + bc;
        if (do_relu) acc = fmaxf(acc, 0.f);
        Y[(size_t)r * out_dim + blockIdx.x * 64 + c] = acc;
    }
}

// -------- small transpose: out[c][r] = in[r][c] --------
__global__ void k_transpose(const float* __restrict__ in, float* __restrict__ out,
                            int R, int C) {
    int idx = blockIdx.x * blockDim.x + threadIdx.x;
    if (idx >= R * C) return;
    int c = idx / R, r = idx % R;
    out[idx] = in[(size_t)r * C + c];
}

__global__ void k_zero(int* __restrict__ p, int n) {
    int i = blockIdx.x * blockDim.x + threadIdx.x;
    if (i < n) p[i] = 0;
}

// -------- cst[p] = scale*(bq . kp[p]) + (mask[p]==0 ? -1e9 : 0) --------
__global__ void k_cst(const float* __restrict__ kp, const float* __restrict__ bq,
                      const float* __restrict__ mask, float* __restrict__ cst) {
    int p = blockIdx.x * blockDim.x + threadIdx.x;
    if (p >= BLn) return;
    float a = dotn((const f4*)bq, (const f4*)(kp + (size_t)p * Hn), Hn >> 2);
    cst[p] = a * 0.088388347648318447f + (mask[p] == 0.f ? -1e9f : 0.f);
}

// -------- codebook squared norms --------
__global__ void k_codenorm(const float* __restrict__ emb, float* __restrict__ c2) {
    int k = blockIdx.x * blockDim.x + threadIdx.x;
    if (k >= Kn) return;
    const f4* e4 = (const f4*)(emb + (size_t)k * Hn);
    float acc = 0.f;
    for (int i = 0; i < Hn / 4; ++i) {
        f4 v = e4[i];
        acc = fmaf(v.x, v.x, acc); acc = fmaf(v.y, v.y, acc);
        acc = fmaf(v.z, v.z, acc); acc = fmaf(v.w, v.w, acc);
    }
    c2[k] = acc;
}

// -------- VQ pick: argmin over dist row (first-index ties) + gather ---------
__global__ __launch_bounds__(128)
void k_vqpick(const float* __restrict__ dist, const float* __restrict__ emb,
              float* __restrict__ zq) {
    const int p = blockIdx.x, tid = threadIdx.x;
    __shared__ int best_s;
    if (tid < 64) {
        float best = 3.0e38f; int bi = 0;
        for (int j = 0; j < 8; ++j) {
            int k = j * 64 + tid;
            float d = dist[(size_t)p * Kn + k];
            if (d < best) { best = d; bi = k; }
        }
        for (int off = 32; off > 0; off >>= 1) {
            float ov = __shfl_xor(best, off);
            int   oi = __shfl_xor(bi, off);
            if (ov < best || (ov == best && oi < bi)) { best = ov; bi = oi; }
        }
        if (tid == 0) best_s = bi;
    }
    __syncthreads();
    zq[(size_t)p * Hn + tid] = emb[(size_t)best_s * Hn + tid];
}

// -------- LSTM: 2 blocks per (batch,dir) x 512 thr; zero-spill --------------
// Proven protocol: tid 0 does store-then-spin in one straight-line region.
__global__ __launch_bounds__(512, 1)
void k_lstm2(const float* __restrict__ xWf, const float* __restrict__ xWb,
             const float* __restrict__ Whh_f, const float* __restrict__ Whh_b,
             float* __restrict__ hcat, float* gxl, int* flags) {
    const int b   = blockIdx.x & 15;
    const int dir = (blockIdx.x >> 4) & 1;
    const int hh  = blockIdx.x >> 5;          // partner = blockIdx ^ 32
    const int tid = threadIdx.x;
    const float* xW  = dir ? xWb : xWf;
    const float* Whh = dir ? Whh_b : Whh_f;

    __shared__ __align__(16) float h_s[Hn];
    __shared__ float g_loc[256];

    const int rl = tid >> 1, chalf = tid & 1;  // 256 rows x 2 threads
    const int grow = (rl >> 6) * 128 + hh * 64 + (rl & 63);

    f4 w[16];
    const f4* Whh4 = (const f4*)Whh;
#pragma unroll
    for (int f = 0; f < 16; ++f) w[f] = Whh4[(size_t)grow * 32 + chalf * 16 + f];
#pragma unroll
    for (int f = 0; f < 16; ++f) asm volatile("" : "+v"(w[f]));

    float c_reg = 0.f;
    if (tid < Hn) h_s[tid] = 0.f;

    float* gx_mine = gxl + ((b * 2 + dir) * 2 + hh) * 128;
    float* gx_peer = gxl + ((b * 2 + dir) * 2 + (hh ^ 1)) * 128;
    int* flag_mine = flags + (b * 4 + dir * 2 + hh) * 32;
    int* flag_peer = flags + (b * 4 + dir * 2 + (hh ^ 1)) * 32;

    const int t0 = dir ? (Ln - 1) : 0;
    float xw_v = (chalf == 0) ? xW[((size_t)b * Ln + t0) * H4n + grow] : 0.f;
    __syncthreads();

    for (int s = 0; s < Ln; ++s) {
        const int t = dir ? (Ln - 1 - s) : s;
        float xw_n = 0.f;
        if (chalf == 0 && s + 1 < Ln) {
            int tn = dir ? (Ln - 2 - s) : (s + 1);
            xw_n = xW[((size_t)b * Ln + tn) * H4n + grow];
        }
        {
            const f4* h4 = (const f4*)(h_s) + chalf * 16;
            float a0 = 0.f, a1 = 0.f, a2 = 0.f, a3 = 0.f;
#pragma unroll
            for (int f = 0; f < 16; f += 4) {
                a0 = fma4v(w[f],     h4[f],     a0);
                a1 = fma4v(w[f + 1], h4[f + 1], a1);
                a2 = fma4v(w[f + 2], h4[f + 2], a2);
                a3 = fma4v(w[f + 3], h4[f + 3], a3);
            }
            float a = (a0 + a1) + (a2 + a3);
            a += __shfl_xor(a, 1);
            if (chalf == 0) g_loc[rl] = a + xw_v;
        }
        __syncthreads();
        if (tid < 64) {
            float ig = sigf(g_loc[tid]);
            float fg = sigf(g_loc[64 + tid]);
            float gg = tanhf(g_loc[128 + tid]);
            float og = sigf(g_loc[192 + tid]);
            c_reg = fg * c_reg + ig * gg;
            float hv = og * tanhf(c_reg);
            int m = hh * 64 + tid;
            h_s[m] = hv;
            hcat[((size_t)b * Ln + t) * (2 * Hn) + dir * Hn + m] = hv;
            __hip_atomic_store(&gx_mine[(s & 1) * 64 + tid], hv,
                               __ATOMIC_RELAXED, __HIP_MEMORY_SCOPE_AGENT);
        }
        __syncthreads();   // drains vmcnt (all data stores complete)
        if (tid == 0) {
            __hip_atomic_store(flag_mine, s + 1, __ATOMIC_SEQ_CST, __HIP_MEMORY_SCOPE_AGENT);
            while (__hip_atomic_load(flag_peer, __ATOMIC_SEQ_CST, __HIP_MEMORY_SCOPE_AGENT) < s + 1) {}
        }
        __syncthreads();
        if (tid < 64)
            h_s[(hh ^ 1) * 64 + tid] =
                __hip_atomic_load(&gx_peer[(s & 1) * 64 + tid],
                                  __ATOMIC_RELAXED, __HIP_MEMORY_SCOPE_AGENT);
        __syncthreads();
        xw_v = xw_n;
    }
}

// -------- decoder: 4 blocks/batch x 256 thr (256-VGPR law), zero-spill ------
// side s owns h[s*32, s*32+32) and gate rows {q*128 + s*32 + j}. Pinned:
// whh 16f4 + wih 16f4 + vwr 64 = 193 VGPR. W1 + KQ l-slice in padded LDS.
// Flag protocol entirely in tid 0 (store SEQ_CST then spin peers SEQ_CST).
__global__ __launch_bounds__(256, 1)
void k_decoder(const float* __restrict__ kq_g, const float* __restrict__ vw_g,
               const float* __restrict__ cst_g,
               const float* __restrict__ W1,  const float* __restrict__ b1_g,
               const float* __restrict__ Wih, const float* __restrict__ Whh,
               const float* __restrict__ bd_g,
               float* gxh, float* gxs, int* fh, int* fs,
               float* __restrict__ dec_out, float* __restrict__ attn_w) {
    const int b    = blockIdx.x & 15;
    const int s    = blockIdx.x >> 4;     // 0..3; {b,b+16,b+32,b+48} same XCD
    const int tid  = threadIdx.x;

    __shared__ __align__(16) f4 kq_s[64 * 33];     // l-slice, padded (33 KB)
    __shared__ __align__(16) f4 w1_s[128 * 17];    // W1 padded (34 KB)
    __shared__ __align__(16) float tok_s[D0n];
    __shared__ __align__(16) float x_s[Hn];
    __shared__ __align__(16) float h_s[Hn];
    __shared__ float g_loc[128];
    __shared__ float s_all[Ln];
    __shared__ float attn_s[Ln];
    __shared__ float cst_s[64];
    __shared__ float b1_s[Hn];

    // ---- pinned weights ----
    const int rl = tid >> 1, ghalf = tid & 1;      // 128 rows x 2 threads
    const int grow = (rl >> 5) * 128 + s * 32 + (rl & 31);
    const f4* Whh4 = (const f4*)Whh;
    const f4* Wih4 = (const f4*)Wih;
    f4 whh[16], wih[16];
#pragma unroll
    for (int f = 0; f < 16; ++f) whh[f] = Whh4[(size_t)grow * 32 + ghalf * 16 + f];
#pragma unroll
    for (int f = 0; f < 16; ++f) wih[f] = Wih4[(size_t)grow * 32 + ghalf * 16 + f];
    float bdr = bd_g[grow];
    const int o = tid >> 2, part = tid & 3;        // out phase map
    float vwr[64];
#pragma unroll
    for (int l = 0; l < 64; ++l)
        vwr[l] = vw_g[((size_t)b * Ln + part * 64 + l) * D0n + o];
#pragma unroll
    for (int f = 0; f < 16; ++f) asm volatile("" : "+v"(whh[f]));
#pragma unroll
    for (int f = 0; f < 16; ++f) asm volatile("" : "+v"(wih[f]));
#pragma unroll
    for (int l = 0; l < 64; ++l) asm volatile("" : "+v"(vwr[l]));
    asm volatile("" : "+v"(bdr));

    // ---- stage LDS: KQ l-slice + W1 ----
    const f4* kq4 = (const f4*)(kq_g + ((size_t)b * Ln + s * 64) * Hn);
#pragma unroll
    for (int it = 0; it < 8; ++it) {
        int idx = it * 256 + tid;                  // 2048 f4
        int l = idx >> 5, f = idx & 31;
        kq_s[l * 33 + f] = kq4[idx];
    }
    const f4* W1_4 = (const f4*)W1;
#pragma unroll
    for (int it = 0; it < 8; ++it) {
        int idx = it * 256 + tid;                  // 2048 f4
        int row = idx >> 4, col = idx & 15;
        w1_s[row * 17 + col] = W1_4[idx];
    }
    if (tid < D0n) tok_s[tid] = 0.f;
    if (tid < Hn)  { h_s[tid] = 0.f; b1_s[tid] = b1_g[tid]; }
    if (tid < 64)  cst_s[tid] = cst_g[(size_t)b * Ln + s * 64 + tid];
    float c_reg = 0.f;
    __syncthreads();

    float* gxh_mine = gxh + ((b * 4 + s) * 2) * 32;
    float* gxs_mine = gxs + ((b * 4 + s) * 2) * 64;
    int* fh_mine = fh + (b * 4 + s) * 32;
    int* fs_mine = fs + (b * 4 + s) * 32;

    for (int t = 0; t < Ln; ++t) {
        // ---- A: x = relu(W1 @ tok + b1); stride-2 interleave (bank-safe) ----
        {
            const f4* t4 = (const f4*)tok_s;
            const f4* wr = w1_s + rl * 17;
            float u0 = 0.f, u1 = 0.f;
#pragma unroll
            for (int k = 0; k < 8; k += 2) {
                u0 = fma4v(wr[ghalf + 2 * k],       t4[ghalf + 2 * k],       u0);
                u1 = fma4v(wr[ghalf + 2 * (k + 1)], t4[ghalf + 2 * (k + 1)], u1);
            }
            float a = u0 + u1;
            a += __shfl_xor(a, 1);
            if (ghalf == 0) x_s[rl] = fmaxf(a + b1_s[rl], 0.f);
        }
        __syncthreads();
        // ---- B: gates (own 128 rows, 2 thr/row), pinned weights ----
        {
            const f4* x4 = (const f4*)x_s + ghalf * 16;
            const f4* h4 = (const f4*)h_s + ghalf * 16;
            float a0 = 0.f, a1 = 0.f, a2 = 0.f, a3 = 0.f;
#pragma unroll
            for (int f = 0; f < 16; f += 4) {
                a0 = fma4v(wih[f],     x4[f],     a0);
                a1 = fma4v(wih[f + 1], x4[f + 1], a1);
                a2 = fma4v(wih[f + 2], x4[f + 2], a2);
                a3 = fma4v(wih[f + 3], x4[f + 3], a3);
            }
#pragma unroll
            for (int f = 0; f < 16; f += 4) {
                a0 = fma4v(whh[f],     h4[f],     a0);
                a1 = fma4v(whh[f + 1], h4[f + 1], a1);
                a2 = fma4v(whh[f + 2], h4[f + 2], a2);
                a3 = fma4v(whh[f + 3], h4[f + 3], a3);
            }
            float a = (a0 + a1) + (a2 + a3);
            a += __shfl_xor(a, 1);
            if (ghalf == 0) g_loc[rl] = a + bdr;
        }
        __syncthreads();
        // ---- C: cell (own 32 comps) + publish h ----
        if (tid < 32) {
            float ig = sigf(g_loc[tid]);
            float fg = sigf(g_loc[32 + tid]);
            float gg = tanhf(g_loc[64 + tid]);
            float og = sigf(g_loc[96 + tid]);
            c_reg = fg * c_reg + ig * gg;
            float hv = og * tanhf(c_reg);
            h_s[s * 32 + tid] = hv;
            __hip_atomic_store(&gxh_mine[(t & 1) * 32 + tid], hv,
                               __ATOMIC_RELAXED, __HIP_MEMORY_SCOPE_AGENT);
        }
        __syncthreads();   // drain
        if (tid == 0) {
            __hip_atomic_store(fh_mine, t + 1, __ATOMIC_SEQ_CST, __HIP_MEMORY_SCOPE_AGENT);
#pragma unroll
            for (int i = 1; i < 4; ++i) {
                int sp = (s + i) & 3;
                int* fp = fh + (b * 4 + sp) * 32;
                while (__hip_atomic_load(fp, __ATOMIC_SEQ_CST, __HIP_MEMORY_SCOPE_AGENT) < t + 1) {}
            }
        }
        __syncthreads();
        if (tid < 96) {
            int spi = tid >> 5;
            int sp = spi + (spi >= s ? 1 : 0);
            int j = tid & 31;
            h_s[sp * 32 + j] = __hip_atomic_load(
                &gxh[((b * 4 + sp) * 2 + (t & 1)) * 32 + j],
                __ATOMIC_RELAXED, __HIP_MEMORY_SCOPE_AGENT);
        }
        __syncthreads();
        // ---- D: scores (own 64 l); stride-4 interleave (bank-safe) ----
        {
            const int l = tid >> 2, dp = tid & 3;
            const f4* h4 = (const f4*)h_s;
            const f4* kr = kq_s + l * 33;
            float u0 = 0.f, u1 = 0.f;
#pragma unroll
            for (int k = 0; k < 8; k += 2) {
                u0 = fma4v(kr[dp + 4 * k],       h4[dp + 4 * k],       u0);
                u1 = fma4v(kr[dp + 4 * (k + 1)], h4[dp + 4 * (k + 1)], u1);
            }
            float a = u0 + u1;
            a += __shfl_xor(a, 1);
            a += __shfl_xor(a, 2);
            if (dp == 0) {
                float val = a + cst_s[l];
                s_all[s * 64 + l] = val;
                __hip_atomic_store(&gxs_mine[(t & 1) * 64 + l], val,
                                   __ATOMIC_RELAXED, __HIP_MEMORY_SCOPE_AGENT);
            }
        }
        __syncthreads();   // drain
        if (tid == 0) {
            __hip_atomic_store(fs_mine, t + 1, __ATOMIC_SEQ_CST, __HIP_MEMORY_SCOPE_AGENT);
#pragma unroll
            for (int i = 1; i < 4; ++i) {
                int sp = (s + i) & 3;
                int* fp = fs + (b * 4 + sp) * 32;
                while (__hip_atomic_load(fp, __ATOMIC_SEQ_CST, __HIP_MEMORY_SCOPE_AGENT) < t + 1) {}
            }
        }
        __syncthreads();
        if (tid < 192) {
            int spi = tid >> 6;
            int sp = spi + (spi >= s ? 1 : 0);
            int l = tid & 63;
            s_all[sp * 64 + l] = __hip_atomic_load(
                &gxs[((b * 4 + sp) * 2 + (t & 1)) * 64 + l],
                __ATOMIC_RELAXED, __HIP_MEMORY_SCOPE_AGENT);
        }
        __syncthreads();
        // ---- E: softmax (wave 0); s==0 writes attn_w ----
        if (tid < 64) {
            float v0 = s_all[tid],       v1 = s_all[tid + 64];
            float v2 = s_all[tid + 128], v3 = s_all[tid + 192];
            float m = fmaxf(fmaxf(v0, v1), fmaxf(v2, v3));
#pragma unroll
            for (int o2 = 32; o2 > 0; o2 >>= 1) m = fmaxf(m, __shfl_xor(m, o2));
            float e0 = expf(v0 - m), e1 = expf(v1 - m);
            float e2 = expf(v2 - m), e3 = expf(v3 - m);
            float ss = (e0 + e1) + (e2 + e3);
#pragma unroll
            for (int o2 = 32; o2 > 0; o2 >>= 1) ss += __shfl_xor(ss, o2);
            float inv = 1.f / ss;
            e0 *= inv; e1 *= inv; e2 *= inv; e3 *= inv;
            attn_s[tid] = e0; attn_s[tid + 64] = e1;
            attn_s[tid + 128] = e2; attn_s[tid + 192] = e3;
            if (s == 0) {
                float* aw = attn_w + ((size_t)b * Ln + t) * Ln;
                aw[tid] = e0; aw[tid + 64] = e1;
                aw[tid + 128] = e2; aw[tid + 192] = e3;
            }
        }
        __syncthreads();
        // ---- F: out[o] = sum_l attn[l]*VW'[l][o]; 64 o x 4 parts ----
        {
            const float* as = attn_s + part * 64;
            float g0 = 0.f, g1 = 0.f, g2 = 0.f, g3 = 0.f;
#pragma unroll
            for (int l = 0; l < 64; l += 4) {
                g0 = fmaf(as[l],     vwr[l],     g0);
                g1 = fmaf(as[l + 1], vwr[l + 1], g1);
                g2 = fmaf(as[l + 2], vwr[l + 2], g2);
                g3 = fmaf(as[l + 3], vwr[l + 3], g3);
            }
            float a = (g0 + g1) + (g2 + g3);
            a += __shfl_xor(a, 1);
            a += __shfl_xor(a, 2);
            if (part == 0) {
                tok_s[o] = a;
                if (s == 0) dec_out[((size_t)b * Ln + t) * D0n + o] = a;
            }
        }
        __syncthreads();
    }
}

extern "C" void kernel_launch(void* const* d_in, const int* in_sizes, int n_in,
                              void* d_out, int out_size, void* d_ws, size_t ws_size,
                              hipStream_t stream) {
    const float* inputs     = (const float*)d_in[0];
    const float* in_mask    = (const float*)d_in[2];
    const float* enc_lin1_W = (const float*)d_in[3];
    const float* enc_lin1_b = (const float*)d_in[4];
    const float* enc_Wih_f  = (const float*)d_in[5];
    const float* enc_Whh_f  = (const float*)d_in[6];
    const float* enc_b_f    = (const float*)d_in[7];
    const float* enc_Wih_b  = (const float*)d_in[8];
    const float* enc_Whh_b  = (const float*)d_in[9];
    const float* enc_b_b    = (const float*)d_in[10];
    const float* enc_lin2_W = (const float*)d_in[11];
    const float* enc_lin2_b = (const float*)d_in[12];
    const float* vq_emb     = (const float*)d_in[13];
    const float* dec_lin1_W = (const float*)d_in[14];
    const float* dec_lin1_b = (const float*)d_in[15];
    const float* dec_Wih    = (const float*)d_in[16];
    const float* dec_Whh    = (const float*)d_in[17];
    const float* dec_b      = (const float*)d_in[18];
    const float* attn_Wq    = (const float*)d_in[19];
    const float* attn_bq    = (const float*)d_in[20];
    const float* attn_Wk    = (const float*)d_in[21];
    const float* attn_bk    = (const float*)d_in[22];
    const float* attn_Wv    = (const float*)d_in[23];
    const float* attn_bv    = (const float*)d_in[24];
    const float* dec_lin2_W = (const float*)d_in[25];
    const float* dec_lin2_b = (const float*)d_in[26];

    float* out     = (float*)d_out;
    float* dec_out = out;                       // 16*256*64   = 262144
    float* attn_w  = out + 262144;              // 16*256*256  = 1048576
    float* ze      = out + 1310720;             // 16*256*128  = 524288
    float* zq      = out + 1835008;             // 16*256*128  = 524288

    float* ws    = (float*)d_ws;
    float* enc_x = ws;                          // 524288
    float* xWf   = enc_x + 524288;              // 2097152
    float* xWb   = xWf + 2097152;               // 2097152
    float* hcat  = xWb + 2097152;               // 1048576
    float* kp    = hcat + 1048576;              // 524288
    float* vp    = kp + 524288;                 // 524288
    float* c2    = vp + 524288;                 // 512
    float* gxh   = c2 + 512;                    // 16*4*2*32  = 4096
    float* gxs   = gxh + 4096;                  // 16*4*2*64  = 8192
    float* gxl   = gxs + 8192;                  // 16*2*2*128 = 8192
    int*   flags = (int*)(gxl + 8192);          // 6144 ints: fh|fs|fl
    int*   fh    = flags;
    int*   fs    = flags + 2048;
    int*   fl    = flags + 4096;
    // aliases into dead regions:
    float* WqT   = enc_x;                       // 16384 (enc_x dead after xW GEMMs)
    float* dist  = xWf;                         // 2097152 (dead post-LSTM)
    float* kq    = xWb;                         // 524288  (dead post-LSTM)
    float* vw    = xWb + 524288;                // 262144
    float* cst   = xWb + 786432;                // 4096

    dim3 blk(256);
    // ---- encoder front ----
    k_gemm<<<dim3(2, 64), blk, 0, stream>>>(inputs, enc_lin1_W, enc_lin1_b, enc_x, D0n, Hn, 1, 1.f);
    k_gemm<<<dim3(8, 64), blk, 0, stream>>>(enc_x, enc_Wih_f, enc_b_f, xWf, Hn, H4n, 0, 1.f);
    k_gemm<<<dim3(8, 64), blk, 0, stream>>>(enc_x, enc_Wih_b, enc_b_b, xWb, Hn, H4n, 0, 1.f);
    k_transpose<<<64, 256, 0, stream>>>(attn_Wq, WqT, Hn, Hn);
    k_zero<<<24, 256, 0, stream>>>(flags, 6144);
    // ---- BiLSTM: 64 blocks = 16b x 2dir x 2half ----
    k_lstm2<<<64, 512, 0, stream>>>(xWf, xWb, enc_Whh_f, enc_Whh_b, hcat, gxl, fl);
    k_gemm<<<dim3(2, 64), blk, 0, stream>>>(hcat, enc_lin2_W, enc_lin2_b, ze, 2 * Hn, Hn, 0, 1.f);
    // ---- VQ ----
    k_codenorm<<<2, 256, 0, stream>>>(vq_emb, c2);
    k_gemm<<<dim3(8, 64), blk, 0, stream>>>(ze, vq_emb, c2, dist, Hn, Kn, 0, -2.f);
    k_vqpick<<<BLn, 128, 0, stream>>>(dist, vq_emb, zq);
    // ---- attention precomputes (dec_in == zq) ----
    k_gemm<<<dim3(2, 64), blk, 0, stream>>>(zq, attn_Wk, attn_bk, kp, Hn, Hn, 0, 1.f);
    k_gemm<<<dim3(2, 64), blk, 0, stream>>>(zq, attn_Wv, attn_bv, vp, Hn, Hn, 0, 1.f);
    k_gemm<<<dim3(2, 64), blk, 0, stream>>>(kp, WqT, nullptr, kq, Hn, Hn, 0, 0.088388347648318447f);
    k_gemm<<<dim3(1, 64), blk, 0, stream>>>(vp, dec_lin2_W, dec_lin2_b, vw, Hn, D0n, 0, 1.f);
    k_cst<<<Bn, 256, 0, stream>>>(kp, attn_bq, in_mask, cst);
    // ---- decoder: 64 blocks = 16 batches x 4 sides, 256 thr ----
    k_decoder<<<64, 256, 0, stream>>>(kq, vw, cst,
                                      dec_lin1_W, dec_lin1_b,
                                      dec_Wih, dec_Whh, dec_b,
                                      gxh, gxs, fh, fs,
                                      dec_out, attn_w);
}